// Round 6
// baseline (256.788 us; speedup 1.0000x reference)
//
#include <hip/hip_runtime.h>
#include <math.h>

#define C    128
#define C4   32
#define NN   2304          // 48*48
#define BN_EPS 1e-5f
#define NEG_INF -3.402823466e38f
#define LOG2E 1.4426950408889634f

typedef short bf16x8 __attribute__((ext_vector_type(8)));
typedef float f32x4 __attribute__((ext_vector_type(4)));

// barrier that only drains LDS (lgkmcnt) — leaves prefetched global loads in flight.
#define SOFT_BARRIER() asm volatile("s_waitcnt lgkmcnt(0)\n\ts_barrier" ::: "memory")

__device__ inline unsigned short f2bf(float f) {
    unsigned int u = __float_as_uint(f);
    u += 0x7fffu + ((u >> 16) & 1u);
    return (unsigned short)(u >> 16);
}

__device__ inline unsigned int pk2bf(float a, float b) {
#if __has_builtin(__builtin_amdgcn_cvt_pk_bf16_f32)
    typedef __bf16 bf2 __attribute__((ext_vector_type(2)));
    bf2 v = __builtin_amdgcn_cvt_pk_bf16_f32(a, b);
    return __builtin_bit_cast(unsigned int, v);
#else
    unsigned int ua = __float_as_uint(a); ua += 0x7fffu + ((ua >> 16) & 1u);
    unsigned int ub = __float_as_uint(b); ub += 0x7fffu + ((ub >> 16) & 1u);
    return __builtin_amdgcn_perm(ub, ua, 0x07060302u);
#endif
}

__device__ inline float fexp2(float x) {
#if __has_builtin(__builtin_amdgcn_exp2f)
    return __builtin_amdgcn_exp2f(x);
#else
    return __expf(x * 0.69314718055994531f);
#endif
}

// ---------------- workspace layout ----------------
// ushort region:
//   Kt  [16][2304][32]  @0         (1179648)   K pre-scaled by log2(e)
//   Qt  [16][2304][32]  @1179648   (1179648)
//   Vf  [16][128][2304] @2359296   (4718592)
//   wkq_bf [32][128]               (4096)
//   wv_bf  [128][128]              (16384)
//   wred_bf[128][256]              (32768)
//   Dp  [16][128][2304] bf16       (4718592)   split-1 unnormalized partial
// float region after:
//   Mn[2][16][2304], Sn[2][16][2304], cs[2][16][2304],
//   kq_sh[32], v_sh[128], red_sh[128]

__global__ __launch_bounds__(256) void k_wprep(
    const float* __restrict__ wkq, const float* __restrict__ kq_g,
    const float* __restrict__ kq_b, const float* __restrict__ kq_m,
    const float* __restrict__ kq_v,
    const float* __restrict__ wv, const float* __restrict__ v_g,
    const float* __restrict__ v_b, const float* __restrict__ v_m,
    const float* __restrict__ v_v,
    const float* __restrict__ wred, const float* __restrict__ red_g,
    const float* __restrict__ red_b, const float* __restrict__ red_m,
    const float* __restrict__ red_v,
    unsigned short* __restrict__ wkq_bf, unsigned short* __restrict__ wv_bf,
    unsigned short* __restrict__ wred_bf,
    float* __restrict__ kq_sh, float* __restrict__ v_sh, float* __restrict__ red_sh)
{
    const int t = blockIdx.x * 256 + threadIdx.x;
    if (t < 4096) {
        const int o = t >> 7;
        const float sc = kq_g[o] * rsqrtf(kq_v[o] + BN_EPS);
        wkq_bf[t] = f2bf(wkq[t] * sc);
        if ((t & 127) == 0) kq_sh[o] = kq_b[o] - kq_m[o] * sc;
    } else if (t < 4096 + 16384) {
        const int e = t - 4096;
        const int o = e >> 7;
        const float sc = v_g[o] * rsqrtf(v_v[o] + BN_EPS);
        wv_bf[e] = f2bf(wv[e] * sc);
        if ((e & 127) == 0) v_sh[o] = v_b[o] - v_m[o] * sc;
    } else if (t < 4096 + 16384 + 32768) {
        const int e = t - 20480;
        const int o = e >> 8;
        const float sc = red_g[o] * rsqrtf(red_v[o] + BN_EPS);
        wred_bf[e] = f2bf(wred[e] * sc);
        if ((e & 255) == 0) red_sh[o] = red_b[o] - red_m[o] * sc;
    }
}

// ---- K/Q conv via MFMA: bf16 transposed out [b][n][32o]; K (z==0) scaled by log2(e)
__global__ __launch_bounds__(256) void k_kq(
    const float* __restrict__ x0, const float* __restrict__ x1,
    const unsigned short* __restrict__ wbf, const float* __restrict__ shift,
    unsigned short* __restrict__ Kt, unsigned short* __restrict__ Qt)
{
    constexpr int NTILE = 128, R = 8;
    __shared__ unsigned short Xs[NTILE][40];

    const int tid = threadIdx.x;
    const int w = tid >> 6, lane = tid & 63;
    const int quad = lane >> 4, l16 = lane & 15;
    const int b = blockIdx.y, n0 = blockIdx.x * NTILE;
    const int nbase = w * 32;

    const float* xin = (blockIdx.z ? x1 : x0) + (size_t)b * C * NN;
    const int p = tid & 15, g = tid >> 4;

    f32x4 acc[2][2];
#pragma unroll
    for (int mt = 0; mt < 2; mt++)
#pragma unroll
        for (int nt = 0; nt < 2; nt++) acc[mt][nt] = (f32x4){0.f, 0.f, 0.f, 0.f};

    for (int c0 = 0; c0 < C; c0 += 32) {
        __syncthreads();
        {
            const float* xr = xin + (size_t)(c0 + 2 * p) * NN + n0 + g * R;
            float av[R], bv[R];
#pragma unroll
            for (int i4 = 0; i4 < R; i4 += 4) {
                *(float4*)&av[i4] = *(const float4*)&xr[i4];
                *(float4*)&bv[i4] = *(const float4*)&xr[NN + i4];
            }
            unsigned int* Xw = (unsigned int*)Xs;
#pragma unroll
            for (int i = 0; i < R; i++)
                Xw[(g * R + i) * 20 + p] = pk2bf(av[i], bv[i]);
        }
        __syncthreads();
        bf16x8 af[2];
#pragma unroll
        for (int mt = 0; mt < 2; mt++)
            af[mt] = *(const bf16x8*)&wbf[(size_t)(mt * 16 + l16) * C + c0 + quad * 8];
#pragma unroll
        for (int nt = 0; nt < 2; nt++) {
            const bf16x8 bfr = *(const bf16x8*)&Xs[nbase + nt * 16 + l16][quad * 8];
#pragma unroll
            for (int mt = 0; mt < 2; mt++)
                acc[mt][nt] = __builtin_amdgcn_mfma_f32_16x16x32_bf16(af[mt], bfr, acc[mt][nt], 0, 0, 0);
        }
    }

    unsigned short* ob16 = blockIdx.z ? Qt : Kt;
    const float osc = blockIdx.z ? 1.f : LOG2E;
#pragma unroll
    for (int mt = 0; mt < 2; mt++)
#pragma unroll
        for (int nt = 0; nt < 2; nt++)
#pragma unroll
            for (int r = 0; r < 4; r++) {
                const int o = mt * 16 + quad * 4 + r;
                const int n = n0 + nbase + nt * 16 + l16;
                const float sh = shift[o];
                ob16[((size_t)b * NN + n) * 32 + o] =
                    f2bf(fmaxf(acc[mt][nt][r] + sh, 0.f) * osc);
            }
}

// ---- fused reduce-conv + V-conv ----
__global__ __launch_bounds__(256) void k_redv(
    const float* __restrict__ xcat,
    const unsigned short* __restrict__ wred_bf, const float* __restrict__ red_sh,
    const unsigned short* __restrict__ wv_bf,  const float* __restrict__ v_sh,
    float* __restrict__ out, unsigned short* __restrict__ Vf)
{
    __shared__ unsigned short Xs[64][40];
    __shared__ unsigned int   Xv[64 * 65];

    const int tid = threadIdx.x;
    const int w = tid >> 6, lane = tid & 63;
    const int quad = lane >> 4, l16 = lane & 15;
    const int b = blockIdx.y, n0 = blockIdx.x * 64;
    const float* xin = xcat + (size_t)b * 2 * C * NN;
    const int p = tid & 15, g = tid >> 4;

    f32x4 acc[2][4];
#pragma unroll
    for (int mt = 0; mt < 2; mt++)
#pragma unroll
        for (int nt = 0; nt < 4; nt++) acc[mt][nt] = (f32x4){0.f, 0.f, 0.f, 0.f};

    for (int c0 = 0; c0 < 2 * C; c0 += 32) {
        __syncthreads();
        {
            const float* xr = xin + (size_t)(c0 + 2 * p) * NN + n0 + g * 4;
            float4 av = *(const float4*)&xr[0];
            float4 bv = *(const float4*)&xr[NN];
            unsigned int* Xw = (unsigned int*)Xs;
            Xw[(g * 4 + 0) * 20 + p] = pk2bf(av.x, bv.x);
            Xw[(g * 4 + 1) * 20 + p] = pk2bf(av.y, bv.y);
            Xw[(g * 4 + 2) * 20 + p] = pk2bf(av.z, bv.z);
            Xw[(g * 4 + 3) * 20 + p] = pk2bf(av.w, bv.w);
        }
        __syncthreads();
        bf16x8 af[2];
#pragma unroll
        for (int mt = 0; mt < 2; mt++)
            af[mt] = *(const bf16x8*)&wred_bf[(size_t)(w * 32 + mt * 16 + l16) * (2 * C) + c0 + quad * 8];
#pragma unroll
        for (int nt = 0; nt < 4; nt++) {
            const bf16x8 bfr = *(const bf16x8*)&Xs[nt * 16 + l16][quad * 8];
#pragma unroll
            for (int mt = 0; mt < 2; mt++)
                acc[mt][nt] = __builtin_amdgcn_mfma_f32_16x16x32_bf16(af[mt], bfr, acc[mt][nt], 0, 0, 0);
        }
    }

    {
        float* ob = out + (size_t)b * (2 * C * NN);
#pragma unroll
        for (int mt = 0; mt < 2; mt++) {
            float sh[4];
#pragma unroll
            for (int r = 0; r < 4; r++) sh[r] = red_sh[w * 32 + mt * 16 + quad * 4 + r];
#pragma unroll
            for (int nt = 0; nt < 4; nt++) {
                const int n = n0 + nt * 16 + l16;
                float v[4];
#pragma unroll
                for (int r = 0; r < 4; r++) {
                    const int o = w * 32 + mt * 16 + quad * 4 + r;
                    v[r] = fmaxf(acc[mt][nt][r] + sh[r], 0.f);
                    ob[(size_t)o * NN + n] = v[r];
                }
                const int op0 = 16 * w + mt * 8 + quad * 2;
                Xv[(op0 + 0) * 65 + nt * 16 + l16] = pk2bf(v[0], v[1]);
                Xv[(op0 + 1) * 65 + nt * 16 + l16] = pk2bf(v[2], v[3]);
            }
        }
    }
    SOFT_BARRIER();

    f32x4 vacc[2][4];
#pragma unroll
    for (int mt = 0; mt < 2; mt++)
#pragma unroll
        for (int nt = 0; nt < 4; nt++) vacc[mt][nt] = (f32x4){0.f, 0.f, 0.f, 0.f};

    for (int c0 = 0; c0 < C; c0 += 32) {
        bf16x8 af[2];
#pragma unroll
        for (int mt = 0; mt < 2; mt++)
            af[mt] = *(const bf16x8*)&wv_bf[(size_t)(w * 32 + mt * 16 + l16) * C + c0 + quad * 8];
#pragma unroll
        for (int nt = 0; nt < 4; nt++) {
            const int col = nt * 16 + l16;
            const int cp0 = c0 / 2 + quad * 4;
            uint4 u;
            u.x = Xv[(cp0 + 0) * 65 + col];
            u.y = Xv[(cp0 + 1) * 65 + col];
            u.z = Xv[(cp0 + 2) * 65 + col];
            u.w = Xv[(cp0 + 3) * 65 + col];
            const bf16x8 bfr = __builtin_bit_cast(bf16x8, u);
#pragma unroll
            for (int mt = 0; mt < 2; mt++)
                vacc[mt][nt] = __builtin_amdgcn_mfma_f32_16x16x32_bf16(af[mt], bfr, vacc[mt][nt], 0, 0, 0);
        }
    }

#pragma unroll
    for (int mt = 0; mt < 2; mt++) {
        float sh[4];
#pragma unroll
        for (int r = 0; r < 4; r++) sh[r] = v_sh[w * 32 + mt * 16 + quad * 4 + r];
#pragma unroll
        for (int nt = 0; nt < 4; nt++)
#pragma unroll
            for (int r = 0; r < 4; r++) {
                const int o = w * 32 + mt * 16 + quad * 4 + r;
                const int n = n0 + nt * 16 + l16;
                Vf[((size_t)b * C + o) * NN + n] = f2bf(fmaxf(vacc[mt][nt][r] + sh[r], 0.f));
            }
    }
}

// ---- flash feat: block = 128c x 64n, m-split over blockIdx.z (2 splits of 1152),
// per-column online softmax; writes unnormalized D + per-column (M,S).
__global__ __launch_bounds__(256) void k_feat(
    const unsigned short* __restrict__ Kt, const unsigned short* __restrict__ Qt,
    const unsigned short* __restrict__ Vf, float* __restrict__ out,
    unsigned short* __restrict__ Dp, float* __restrict__ Mn, float* __restrict__ Sn)
{
    __shared__ __align__(16) unsigned short Et[64][72];
    __shared__ float cmax[4][64];
    const int tid = threadIdx.x;
    const int w = tid >> 6, lane = tid & 63;
    const int quad = lane >> 4, l16 = lane & 15;
    const int b = blockIdx.y, n0 = blockIdx.x * 64, split = blockIdx.z;
    const int mlo = split * (NN / 2), mhi = mlo + NN / 2;
    const unsigned short* Kb = Kt + (size_t)b * NN * 32;
    const unsigned short* Qb = Qt + (size_t)b * NN * 32;
    const unsigned short* Vb = Vf + (size_t)b * C * NN;

    bf16x8 kf[4];
#pragma unroll
    for (int nt = 0; nt < 4; nt++)
        kf[nt] = *(const bf16x8*)&Kb[(size_t)(n0 + nt * 16 + l16) * 32 + quad * 8];

    f32x4 acc[2][4];
#pragma unroll
    for (int i = 0; i < 2; i++)
#pragma unroll
        for (int j = 0; j < 4; j++) acc[i][j] = (f32x4){0.f, 0.f, 0.f, 0.f};
    float Mcol[4], Scol[4];
#pragma unroll
    for (int nt = 0; nt < 4; nt++) { Mcol[nt] = NEG_INF; Scol[nt] = 0.f; }

    bf16x8 qc = *(const bf16x8*)&Qb[(size_t)(mlo + w * 16 + l16) * 32 + quad * 8];
    bf16x8 vc[2][2];
#pragma unroll
    for (int ct = 0; ct < 2; ct++)
#pragma unroll
        for (int ks = 0; ks < 2; ks++)
            vc[ct][ks] = *(const bf16x8*)&Vb[(size_t)(w * 32 + ct * 16 + l16) * NN + mlo + ks * 32 + quad * 8];

    for (int m0 = mlo; m0 < mhi; m0 += 64) {
        // S phase
        f32x4 s[4];
#pragma unroll
        for (int nt = 0; nt < 4; nt++) {
            f32x4 z = (f32x4){0.f, 0.f, 0.f, 0.f};
            s[nt] = __builtin_amdgcn_mfma_f32_16x16x32_bf16(qc, kf[nt], z, 0, 0, 0);
        }
        // prefetch next chunk
        const int m1 = (m0 + 64 < mhi) ? m0 + 64 : mlo;
        bf16x8 qn = *(const bf16x8*)&Qb[(size_t)(m1 + w * 16 + l16) * 32 + quad * 8];
        bf16x8 vn[2][2];
#pragma unroll
        for (int ct = 0; ct < 2; ct++)
#pragma unroll
            for (int ks = 0; ks < 2; ks++)
                vn[ct][ks] = *(const bf16x8*)&Vb[(size_t)(w * 32 + ct * 16 + l16) * NN + m1 + ks * 32 + quad * 8];

        // per-column chunk max: intra-lane, cross-quad, then cross-wave (LDS)
        float cm[4];
#pragma unroll
        for (int nt = 0; nt < 4; nt++) {
            cm[nt] = fmaxf(fmaxf(s[nt][0], s[nt][1]), fmaxf(s[nt][2], s[nt][3]));
            cm[nt] = fmaxf(cm[nt], __shfl_xor(cm[nt], 16));
            cm[nt] = fmaxf(cm[nt], __shfl_xor(cm[nt], 32));
        }
        if (lane < 16) {
#pragma unroll
            for (int nt = 0; nt < 4; nt++) cmax[w][nt * 16 + lane] = cm[nt];
        }
        SOFT_BARRIER();   // B1: cmax visible
        float scale[4];
#pragma unroll
        for (int nt = 0; nt < 4; nt++) {
            const int col = nt * 16 + l16;
            const float m4 = fmaxf(fmaxf(cmax[0][col], cmax[1][col]),
                                   fmaxf(cmax[2][col], cmax[3][col]));
            const float newM = fmaxf(Mcol[nt], m4);
            scale[nt] = fexp2(Mcol[nt] - newM);
            Mcol[nt] = newM;
        }
        // rescale acc + Scol; compute E, pack, stage
#pragma unroll
        for (int nt = 0; nt < 4; nt++) {
            acc[0][nt] *= scale[nt];
            acc[1][nt] *= scale[nt];
            const float e0 = fexp2(s[nt][0] - Mcol[nt]);
            const float e1 = fexp2(s[nt][1] - Mcol[nt]);
            const float e2 = fexp2(s[nt][2] - Mcol[nt]);
            const float e3 = fexp2(s[nt][3] - Mcol[nt]);
            Scol[nt] = Scol[nt] * scale[nt] + ((e0 + e1) + (e2 + e3));
            *(uint2*)&Et[nt * 16 + l16][w * 16 + quad * 4] =
                make_uint2(pk2bf(e0, e1), pk2bf(e2, e3));
        }
        SOFT_BARRIER();   // B2: Et visible
        // PV phase
#pragma unroll
        for (int ks = 0; ks < 2; ks++) {
#pragma unroll
            for (int nt = 0; nt < 4; nt++) {
                const bf16x8 ef = *(const bf16x8*)&Et[nt * 16 + l16][ks * 32 + quad * 8];
                acc[0][nt] = __builtin_amdgcn_mfma_f32_16x16x32_bf16(vc[0][ks], ef, acc[0][nt], 0, 0, 0);
                acc[1][nt] = __builtin_amdgcn_mfma_f32_16x16x32_bf16(vc[1][ks], ef, acc[1][nt], 0, 0, 0);
            }
        }
        qc = qn;
#pragma unroll
        for (int ct = 0; ct < 2; ct++)
#pragma unroll
            for (int ks = 0; ks < 2; ks++) vc[ct][ks] = vn[ct][ks];
    }

    // merge Scol: cross-quad, then cross-wave via cmax buffer
#pragma unroll
    for (int nt = 0; nt < 4; nt++) {
        Scol[nt] += __shfl_xor(Scol[nt], 16);
        Scol[nt] += __shfl_xor(Scol[nt], 32);
    }
    SOFT_BARRIER();       // all PV Et-reads done; safe to reuse cmax
    if (lane < 16) {
#pragma unroll
        for (int nt = 0; nt < 4; nt++) cmax[w][nt * 16 + lane] = Scol[nt];
    }
    SOFT_BARRIER();
    if (w == 0 && lane < 16) {
        float* Mb = Mn + ((size_t)split * 16 + b) * NN + n0;
        float* Sb = Sn + ((size_t)split * 16 + b) * NN + n0;
#pragma unroll
        for (int nt = 0; nt < 4; nt++) {
            const int col = nt * 16 + lane;
            Mb[col] = Mcol[nt];
            Sb[col] = cmax[0][col] + cmax[1][col] + cmax[2][col] + cmax[3][col];
        }
    }

    // write unnormalized D
    if (split == 0) {
        float* ob = out + (size_t)b * 2 * C * NN + (size_t)C * NN + n0;
#pragma unroll
        for (int ct = 0; ct < 2; ct++)
#pragma unroll
            for (int nt = 0; nt < 4; nt++)
#pragma unroll
                for (int r = 0; r < 4; r++) {
                    const int c = w * 32 + ct * 16 + quad * 4 + r;
                    ob[(size_t)c * NN + nt * 16 + l16] = acc[ct][nt][r];
                }
    } else {
        unsigned short* db = Dp + (size_t)b * C * NN + n0;
#pragma unroll
        for (int ct = 0; ct < 2; ct++)
#pragma unroll
            for (int nt = 0; nt < 4; nt++)
#pragma unroll
                for (int r = 0; r < 4; r++) {
                    const int c = w * 32 + ct * 16 + quad * 4 + r;
                    db[(size_t)c * NN + nt * 16 + l16] = f2bf(acc[ct][nt][r]);
                }
    }
}

// global (Mg,Sg) per batch, then per-column scale factors cs[s][b][n]
__global__ __launch_bounds__(256) void k_fin2(
    const float* __restrict__ Mn, const float* __restrict__ Sn,
    float* __restrict__ cs)
{
    __shared__ float rmax[256], rsum[256];
    const int b = blockIdx.x, tid = threadIdx.x;
    float lmax = NEG_INF, lsum = 0.f;
#pragma unroll
    for (int s = 0; s < 2; s++) {
        const float* Mb = Mn + ((size_t)s * 16 + b) * NN;
        const float* Sb = Sn + ((size_t)s * 16 + b) * NN;
        for (int i = tid; i < NN; i += 256) {
            const float m = Mb[i], sv = Sb[i];
            const float nmax = fmaxf(lmax, m);
            lsum = lsum * fexp2(lmax - nmax) + sv * fexp2(m - nmax);
            lmax = nmax;
        }
    }
    rmax[tid] = lmax; rsum[tid] = lsum;
    __syncthreads();
    for (int st = 128; st > 0; st >>= 1) {
        if (tid < st) {
            const float m2 = rmax[tid + st], s2 = rsum[tid + st];
            const float nmax = fmaxf(rmax[tid], m2);
            rsum[tid] = rsum[tid] * fexp2(rmax[tid] - nmax) + s2 * fexp2(m2 - nmax);
            rmax[tid] = nmax;
        }
        __syncthreads();
    }
    const float Mg = rmax[0];
    const float rS = 1.f / rsum[0];
#pragma unroll
    for (int s = 0; s < 2; s++) {
        const float* Mb = Mn + ((size_t)s * 16 + b) * NN;
        float* cb = cs + ((size_t)s * 16 + b) * NN;
        for (int i = tid; i < NN; i += 256)
            cb[i] = fexp2(Mb[i] - Mg) * rS;
    }
}

// out[b][128+c][n] = D0*cs0[n] + D1*cs1[n]
__global__ __launch_bounds__(256) void k_scale(
    float* __restrict__ out, const unsigned short* __restrict__ Dp,
    const float* __restrict__ cs)
{
    const size_t e = ((size_t)blockIdx.x * 256 + threadIdx.x) * 4;
    const int b = (int)(e / (C * NN));
    const int r = (int)(e % (C * NN));
    const int c = r / NN, n = r % NN;

    float* op = out + (size_t)b * 2 * C * NN + (size_t)(C + c) * NN + n;
    float4 d0 = *(const float4*)op;
    const ushort4 d1u = *(const ushort4*)&Dp[((size_t)b * C + c) * NN + n];
    const float4 f0 = *(const float4*)&cs[(size_t)b * NN + n];
    const float4 f1 = *(const float4*)&cs[(size_t)(16 + b) * NN + n];

    float4 o;
    o.x = d0.x * f0.x + __uint_as_float((unsigned int)d1u.x << 16) * f1.x;
    o.y = d0.y * f0.y + __uint_as_float((unsigned int)d1u.y << 16) * f1.y;
    o.z = d0.z * f0.z + __uint_as_float((unsigned int)d1u.z << 16) * f1.z;
    o.w = d0.w * f0.w + __uint_as_float((unsigned int)d1u.w << 16) * f1.w;
    *(float4*)op = o;
}

extern "C" void kernel_launch(void* const* d_in, const int* in_sizes, int n_in,
                              void* d_out, int out_size, void* d_ws, size_t ws_size,
                              hipStream_t stream)
{
    const float* x_en   = (const float*)d_in[0];
    const float* x_de   = (const float*)d_in[1];
    const float* x_cat  = (const float*)d_in[2];
    const float* w_kq   = (const float*)d_in[3];
    const float* kq_g   = (const float*)d_in[4];
    const float* kq_b   = (const float*)d_in[5];
    const float* kq_m   = (const float*)d_in[6];
    const float* kq_v   = (const float*)d_in[7];
    const float* w_v    = (const float*)d_in[8];
    const float* v_g    = (const float*)d_in[9];
    const float* v_b    = (const float*)d_in[10];
    const float* v_m    = (const float*)d_in[11];
    const float* v_v    = (const float*)d_in[12];
    const float* w_red  = (const float*)d_in[13];
    const float* red_g  = (const float*)d_in[14];
    const float* red_b  = (const float*)d_in[15];
    const float* red_m  = (const float*)d_in[16];
    const float* red_v  = (const float*)d_in[17];

    unsigned short* Kt      = (unsigned short*)d_ws;
    unsigned short* Qt      = Kt + 1179648;
    unsigned short* Vf      = Qt + 1179648;
    unsigned short* wkq_bf  = Vf + 4718592;
    unsigned short* wv_bf   = wkq_bf + 4096;
    unsigned short* wred_bf = wv_bf + 16384;
    unsigned short* Dp      = wred_bf + 32768;
    float* Mn   = (float*)(Dp + 4718592);
    float* Sn   = Mn + 2 * 16 * NN;
    float* cs   = Sn + 2 * 16 * NN;
    float* kq_sh  = cs + 2 * 16 * NN;
    float* v_sh   = kq_sh + 32;
    float* red_sh = v_sh + 128;
    float* out  = (float*)d_out;

    k_wprep<<<208, 256, 0, stream>>>(
        w_kq, kq_g, kq_b, kq_m, kq_v,
        w_v, v_g, v_b, v_m, v_v,
        w_red, red_g, red_b, red_m, red_v,
        wkq_bf, wv_bf, wred_bf, kq_sh, v_sh, red_sh);

    k_kq  <<<dim3(18, 16, 2), 256, 0, stream>>>(x_en, x_de, wkq_bf, kq_sh, Kt, Qt);
    k_redv<<<dim3(36, 16), 256, 0, stream>>>(x_cat, wred_bf, red_sh, wv_bf, v_sh, out, Vf);

    k_feat <<<dim3(36, 16, 2), 256, 0, stream>>>(Kt, Qt, Vf, out, Dp, Mn, Sn);
    k_fin2 <<<16, 256, 0, stream>>>(Mn, Sn, cs);
    k_scale<<<4608, 256, 0, stream>>>(out, Dp, cs);
}